// Round 6
// baseline (181.650 us; speedup 1.0000x reference)
//
#include <hip/hip_runtime.h>
#include <hip/hip_bf16.h>
#include <math.h>

#define S_LEN 2048
#define BSZ 2
#define DM 512
#define NH 8
#define HD 64
#define RTOT (S_LEN*BSZ)             // 4096 rows, row r = s*BSZ + b
#define T_KEEP 32
#define ROW0 ((S_LEN - T_KEEP)*BSZ)  // 4032
#define NXELEM (RTOT*DM)             // 2097152
#define NWROW  (NH*192)              // 1536
#define NWELEM (NWROW*DM)            // 786432

typedef __attribute__((ext_vector_type(8))) short short8;
typedef __attribute__((ext_vector_type(4))) float floatx4;

__device__ __forceinline__ void gld16(const void* g, void* l) {
    __builtin_amdgcn_global_load_lds((const __attribute__((address_space(1))) void*)g,
                                     (__attribute__((address_space(3))) void*)l, 16, 0, 0);
}

__device__ __forceinline__ void cvt2(float v, short& hs, short& ls) {
    __hip_bfloat16 h = __float2bfloat16(v);
    float hf = __bfloat162float(h);
    __hip_bfloat16 l = __float2bfloat16(v - hf);
    hs = __builtin_bit_cast(short, h);
    ls = __builtin_bit_cast(short, l);
}

// ---- Kernel 0: fp32 -> bf16 hi/lo planes + bias concat + gbar zero + bg fill --
__global__ __launch_bounds__(256) void convert(
    const float* __restrict__ x,
    const float* __restrict__ Wq, const float* __restrict__ Wk, const float* __restrict__ Wv,
    const float* __restrict__ bq, const float* __restrict__ bk, const float* __restrict__ bv,
    const float* __restrict__ bo,
    short* __restrict__ xh, short* __restrict__ xl,
    short* __restrict__ wh, short* __restrict__ wl, float* __restrict__ bcat,
    float* __restrict__ gbar, float* __restrict__ out)
{
    const int g = blockIdx.x*blockDim.x + threadIdx.x;
    const int stride = gridDim.x*blockDim.x;
    const int total4 = (NXELEM + NWELEM)/4;
    for (int i = g; i < total4; i += stride) {
        float4 v; size_t dst;
        short* dh; short* dl;
        if (i < NXELEM/4) {
            v = ((const float4*)x)[i];
            dst = (size_t)i*4; dh = xh; dl = xl;
        } else {
            int j = i - NXELEM/4;
            int e = j*4;
            int R = e >> 9;
            int k = e & 511;
            int t = R >> 6;                 // = h*3 + m
            int hh = (t*683) >> 11;         // t/3 for t<24
            int m = t - 3*hh;
            int c = R & 63;
            const float* W = (m == 0 ? Wq : (m == 1 ? Wk : Wv));
            v = *(const float4*)&W[(size_t)(hh*HD + c)*DM + k];
            dst = (size_t)R*DM + k; dh = wh; dl = wl;
        }
        short4 hv, lv;
        cvt2(v.x, hv.x, lv.x); cvt2(v.y, hv.y, lv.y);
        cvt2(v.z, hv.z, lv.z); cvt2(v.w, hv.w, lv.w);
        *(short4*)&dh[dst] = hv;
        *(short4*)&dl[dst] = lv;
    }
    // background fill: rows < ROW0 of out are just bo
    {
        const float4* b4 = (const float4*)bo;
        float4* o4 = (float4*)out;
        const int fill4 = ROW0*DM/4;
        for (int i = g; i < fill4; i += stride) o4[i] = b4[i & 127];
    }
    if (g < NWROW) {
        int t = g >> 6;
        int hh = (t*683) >> 11;
        int m = t - 3*hh;
        int c = g & 63;
        bcat[g] = (m == 0 ? bq : (m == 1 ? bk : bv))[hh*HD + c];
    }
    if (g < 2048) gbar[g] = 0.f;
}

// ------------- Kernel 1: MFMA split-bf16 qkv GEMM + sigma accumulation ---------
// grid (64, 8): block = 64 rows x head h's 192 cols. BK=32, 16 K-iterations.
// LDS 32KB stage: A_hi[4K] A_lo[4K] B_hi[12K] B_lo[12K] in 1KB frag chunks.
// C dumped/processed in two 32-row halves reusing the stage -> 4 blocks/CU.
__global__ __launch_bounds__(256, 4) void qkv_gemm(
    const short* __restrict__ xh, const short* __restrict__ xl,
    const short* __restrict__ wh, const short* __restrict__ wl,
    const float* __restrict__ bcat, const float* __restrict__ beta,
    float* __restrict__ gbar, float* __restrict__ qsel)
{
    __shared__ __align__(16) char smem[32768];
    __shared__ float sb[256];

    const int tid  = threadIdx.x;
    const int w    = tid >> 6;
    const int lane = tid & 63;
    const int lrow = lane & 15;
    const int lk8  = lane >> 4;
    const int h    = blockIdx.y;
    const int r0   = blockIdx.x * 64;
    const int rowg = w >> 1;
    const int colg = w & 1;

    floatx4 acc[2][6];
    #pragma unroll
    for (int i = 0; i < 2; ++i)
        #pragma unroll
        for (int j = 0; j < 6; ++j) acc[i][j] = (floatx4)0.f;

    // staging: wave w stages A chunk w (both planes) and B chunks 3w..3w+2 (both planes)
    const size_t aoff = (size_t)(r0 + w*16 + lrow)*DM + lk8*8;
    const size_t boff = (size_t)(h*192 + 3*w*16 + lrow)*DM + lk8*8;
    const short* asrc[2] = { xh + aoff, xl + aoff };
    const short* bsrc[2] = { wh + boff, wl + boff };

    for (int kc = 0; kc < 16; ++kc) {
        const int ko = kc*32;
        #pragma unroll
        for (int p = 0; p < 2; ++p) {
            gld16(asrc[p] + ko, smem + p*4096 + w*1024);
            #pragma unroll
            for (int jj = 0; jj < 3; ++jj)
                gld16(bsrc[p] + (size_t)jj*16*DM + ko,
                      smem + 8192 + p*12288 + (3*w + jj)*1024);
        }
        __syncthreads();
        short8 ah[2], al[2];
        #pragma unroll
        for (int i = 0; i < 2; ++i) {
            ah[i] = *(const short8*)(smem + (rowg*2 + i)*1024 + lane*16);
            al[i] = *(const short8*)(smem + 4096 + (rowg*2 + i)*1024 + lane*16);
        }
        #pragma unroll
        for (int j = 0; j < 6; ++j) {
            short8 bh = *(const short8*)(smem + 8192 + (colg*6 + j)*1024 + lane*16);
            short8 bl = *(const short8*)(smem + 20480 + (colg*6 + j)*1024 + lane*16);
            #pragma unroll
            for (int i = 0; i < 2; ++i) {
                acc[i][j] = __builtin_amdgcn_mfma_f32_16x16x32_bf16(ah[i], bh, acc[i][j], 0, 0, 0);
                acc[i][j] = __builtin_amdgcn_mfma_f32_16x16x32_bf16(al[i], bh, acc[i][j], 0, 0, 0);
                acc[i][j] = __builtin_amdgcn_mfma_f32_16x16x32_bf16(ah[i], bl, acc[i][j], 0, 0, 0);
            }
        }
        __syncthreads();
    }

    // epilogue in two 32-row halves (Cl = 32x192 fp32 = 24KB, fits in stage)
    float* Cl = (float*)smem;
    sb[tid] = 0.f;
    const float inv_scale = 1.0f / (8.0f * expf(beta[h]));
    float kacc0 = 0.f, kacc1 = 0.f, vacc0 = 0.f, vacc1 = 0.f;

    #pragma unroll
    for (int half = 0; half < 2; ++half) {
        if (rowg == half) {
            #pragma unroll
            for (int i = 0; i < 2; ++i) {
                #pragma unroll
                for (int j = 0; j < 6; ++j) {
                    int col = colg*96 + j*16 + lrow;
                    float bias = bcat[h*192 + col];
                    #pragma unroll
                    for (int reg = 0; reg < 4; ++reg) {
                        int row = i*16 + lk8*4 + reg;   // 0..31 within half
                        Cl[row*192 + col] = acc[i][j][reg] + bias;
                    }
                }
            }
        }
        __syncthreads();
        for (int i2 = w; i2 < 32; i2 += 4) {
            float qv = Cl[i2*192 + lane];
            float kv = Cl[i2*192 + 64 + lane];
            float vv = Cl[i2*192 + 128 + lane];
            int r = r0 + half*32 + i2;
            int s = r >> 1;
            int b = r & 1;
            if ((s & 63) == 63) {
                int wi = s >> 6;
                qsel[((size_t)(b*NH + h)*T_KEEP + wi)*64 + lane] = qv;
            }
            float p = qv * kv;
            #pragma unroll
            for (int off = 32; off > 0; off >>= 1) p += __shfl_xor(p, off, 64);
            float sig = 1.0f / (1.0f + expf(-p * inv_scale));
            if (b == 0) { kacc0 += sig*kv; vacc0 += sig*vv; }
            else        { kacc1 += sig*kv; vacc1 += sig*vv; }
        }
        __syncthreads();
    }

    atomicAdd(&sb[  0 + lane], kacc0);
    atomicAdd(&sb[ 64 + lane], vacc0);
    atomicAdd(&sb[128 + lane], kacc1);
    atomicAdd(&sb[192 + lane], vacc1);
    __syncthreads();
    {
        int b   = tid >> 7;
        int sel = (tid >> 6) & 1;
        int j   = tid & 63;
        int z   = b*NH + h;
        atomicAdd(&gbar[sel*1024 + z*64 + j], sb[tid]);
    }
}

// ------------- Kernel 2: fused softmax-coef + G + output rows ------------------
// grid 128 x 256: block handles 4 output columns (cp = bx*4 + wave).
// Phase 1 (per block): coef[b][h][wi] table from qsel/gbar (cheap, duplicated).
// Phase 2: per wave, G[b][h] for its cp via coalesced Wo reads; write 64 rows.
__global__ __launch_bounds__(256) void outk2(
    const float* __restrict__ qsel, const float* __restrict__ beta,
    const float* __restrict__ gbar, const float* __restrict__ Wo,
    const float* __restrict__ bo, float* __restrict__ out)
{
    const int tid = threadIdx.x;
    const int w = tid >> 6;
    const int lane = tid & 63;

    __shared__ float s_sc[16][T_KEEP];
    __shared__ float s_cw[16][T_KEEP];
    __shared__ float s_out[64*4];

    // phase 1: scores
    #pragma unroll
    for (int pp = 0; pp < 4; ++pp) {
        int z = w*4 + pp;    // b*8 + h
        float kb = gbar[z*64 + lane];
        for (int wi = 0; wi < T_KEEP; ++wi) {
            float p = qsel[((size_t)z*T_KEEP + wi)*64 + lane] * kb;
            #pragma unroll
            for (int off = 32; off > 0; off >>= 1) p += __shfl_xor(p, off, 64);
            if (lane == 0) s_sc[z][wi] = p;
        }
    }
    __syncthreads();
    if (tid < 16) {
        int h = tid & 7;
        float inv_scale = 1.0f / (8.0f * expf(beta[h]));
        float mx = 0.f;  // sink score = 0
        for (int wi = 0; wi < T_KEEP; ++wi) mx = fmaxf(mx, s_sc[tid][wi]*inv_scale);
        float denom = expf(-mx);
        for (int wi = 0; wi < T_KEEP; ++wi) denom += expf(s_sc[tid][wi]*inv_scale - mx);
        for (int wi = 0; wi < T_KEEP; ++wi) {
            float c = expf(s_sc[tid][wi]*inv_scale - mx) / denom;
            if (wi == T_KEEP-1) c += 1.0f;
            s_cw[tid][wi] = c;
        }
    }
    __syncthreads();

    // phase 2: G + output
    const int cp = blockIdx.x*4 + w;
    float g[2][NH];
    #pragma unroll
    for (int h = 0; h < NH; ++h) {
        float wv = Wo[(size_t)cp*DM + h*64 + lane];
        #pragma unroll
        for (int b = 0; b < 2; ++b) {
            float p = gbar[1024 + (b*NH + h)*64 + lane] * wv;
            #pragma unroll
            for (int off = 32; off > 0; off >>= 1) p += __shfl_xor(p, off, 64);
            g[b][h] = p;   // butterfly -> all lanes hold the sum
        }
    }
    {
        int b = lane & 1, wi = lane >> 1;   // lane = a = wi*2 + b
        float accv = bo[cp];
        #pragma unroll
        for (int h = 0; h < NH; ++h) accv += s_cw[b*8 + h][wi] * g[b][h];
        s_out[lane*4 + w] = accv;
    }
    __syncthreads();
    {
        int a = tid >> 2, cc = tid & 3;
        out[(size_t)(ROW0 + a)*DM + blockIdx.x*4 + cc] = s_out[a*4 + cc];
    }
}

extern "C" void kernel_launch(void* const* d_in, const int* in_sizes, int n_in,
                              void* d_out, int out_size, void* d_ws, size_t ws_size,
                              hipStream_t stream) {
    const float* x    = (const float*)d_in[0];
    const float* Wq   = (const float*)d_in[1];
    const float* bq   = (const float*)d_in[2];
    const float* Wk   = (const float*)d_in[3];
    const float* bk   = (const float*)d_in[4];
    const float* Wv   = (const float*)d_in[5];
    const float* bv   = (const float*)d_in[6];
    const float* Wo   = (const float*)d_in[7];
    const float* bo   = (const float*)d_in[8];
    const float* beta = (const float*)d_in[9];

    char* ws = (char*)d_ws;
    float* gbar = (float*)(ws + 0);           //   8 KB
    float* qsel = (float*)(ws + 8192);        // 128 KB
    float* bcat = (float*)(ws + 139264);      //   8 KB
    short* xh   = (short*)(ws + 147456);      //   4 MB
    short* xl   = (short*)(ws + 147456 + 4194304);
    short* wh   = (short*)(ws + 147456 + 2*4194304);
    short* wl   = (short*)(ws + 147456 + 2*4194304 + 1572864);
    float* out  = (float*)d_out;

    convert<<<1024, 256, 0, stream>>>(x, Wq, Wk, Wv, bq, bk, bv, bo,
                                      xh, xl, wh, wl, bcat, gbar, out);
    dim3 g1(RTOT/64, NH);
    qkv_gemm<<<g1, 256, 0, stream>>>(xh, xl, wh, wl, bcat, beta, gbar, qsel);
    outk2<<<128, 256, 0, stream>>>(qsel, beta, gbar, Wo, bo, out);
}

// Round 7
// 160.045 us; speedup vs baseline: 1.1350x; 1.1350x over previous
//
#include <hip/hip_runtime.h>
#include <hip/hip_bf16.h>
#include <math.h>

#define S_LEN 2048
#define BSZ 2
#define DM 512
#define NH 8
#define HD 64
#define RTOT (S_LEN*BSZ)             // 4096 rows, row r = s*BSZ + b
#define T_KEEP 32
#define ROW0 ((S_LEN - T_KEEP)*BSZ)  // 4032
#define NXELEM (RTOT*DM)             // 2097152
#define NWROW  (NH*192)              // 1536
#define NWELEM (NWROW*DM)            // 786432

typedef __attribute__((ext_vector_type(8))) short short8;
typedef __attribute__((ext_vector_type(4))) float floatx4;

__device__ __forceinline__ void cvt2(float v, short& hs, short& ls) {
    __hip_bfloat16 h = __float2bfloat16(v);
    float hf = __bfloat162float(h);
    __hip_bfloat16 l = __float2bfloat16(v - hf);
    hs = __builtin_bit_cast(short, h);
    ls = __builtin_bit_cast(short, l);
}

// ---- Kernel 0: fp32 -> bf16 hi/lo planes + bias concat + gbar zero + bg fill --
__global__ __launch_bounds__(256) void convert(
    const float* __restrict__ x,
    const float* __restrict__ Wq, const float* __restrict__ Wk, const float* __restrict__ Wv,
    const float* __restrict__ bq, const float* __restrict__ bk, const float* __restrict__ bv,
    const float* __restrict__ bo,
    short* __restrict__ xh, short* __restrict__ xl,
    short* __restrict__ wh, short* __restrict__ wl, float* __restrict__ bcat,
    float* __restrict__ gbar, float* __restrict__ out)
{
    const int g = blockIdx.x*blockDim.x + threadIdx.x;
    const int stride = gridDim.x*blockDim.x;
    const int total4 = (NXELEM + NWELEM)/4;
    for (int i = g; i < total4; i += stride) {
        float4 v; size_t dst;
        short* dh; short* dl;
        if (i < NXELEM/4) {
            v = ((const float4*)x)[i];
            dst = (size_t)i*4; dh = xh; dl = xl;
        } else {
            int j = i - NXELEM/4;
            int e = j*4;
            int R = e >> 9;
            int k = e & 511;
            int t = R >> 6;                 // = h*3 + m
            int hh = (t*683) >> 11;         // t/3 for t<24
            int m = t - 3*hh;
            int c = R & 63;
            const float* W = (m == 0 ? Wq : (m == 1 ? Wk : Wv));
            v = *(const float4*)&W[(size_t)(hh*HD + c)*DM + k];
            dst = (size_t)R*DM + k; dh = wh; dl = wl;
        }
        short4 hv, lv;
        cvt2(v.x, hv.x, lv.x); cvt2(v.y, hv.y, lv.y);
        cvt2(v.z, hv.z, lv.z); cvt2(v.w, hv.w, lv.w);
        *(short4*)&dh[dst] = hv;
        *(short4*)&dl[dst] = lv;
    }
    // background fill: rows < ROW0 of out are just bo
    {
        const float4* b4 = (const float4*)bo;
        float4* o4 = (float4*)out;
        const int fill4 = ROW0*DM/4;
        for (int i = g; i < fill4; i += stride) o4[i] = b4[i & 127];
    }
    if (g < NWROW) {
        int t = g >> 6;
        int hh = (t*683) >> 11;
        int m = t - 3*hh;
        int c = g & 63;
        bcat[g] = (m == 0 ? bq : (m == 1 ? bk : bv))[hh*HD + c];
    }
    if (g < 2048) gbar[g] = 0.f;
}

// ------------- Kernel 1: MFMA split-bf16 qkv GEMM, barrier-free K loop ---------
// grid (64, 8): block = 64 rows x head h's 192 cols. Waves 2x2 (32r x 96c each).
// Fragments loaded DIRECTLY from global (fragment layout == memory layout:
// lane l -> row l&15, k (l>>4)*8, 16B). No LDS / no syncthreads in K loop.
// 2-stage software pipeline over kc (BK=32, 16 iterations).
__global__ __launch_bounds__(256) void qkv_gemm(
    const short* __restrict__ xh, const short* __restrict__ xl,
    const short* __restrict__ wh, const short* __restrict__ wl,
    const float* __restrict__ bcat, const float* __restrict__ beta,
    float* __restrict__ gbar, float* __restrict__ qsel)
{
    __shared__ __align__(16) float Cl[32*192];   // 24KB C-dump (two halves)
    __shared__ float sb[256];

    const int tid  = threadIdx.x;
    const int w    = tid >> 6;
    const int lane = tid & 63;
    const int lrow = lane & 15;
    const int lk8  = lane >> 4;
    const int h    = blockIdx.y;
    const int r0   = blockIdx.x * 64;
    const int rowg = w >> 1;
    const int colg = w & 1;

    floatx4 acc[2][6];
    #pragma unroll
    for (int i = 0; i < 2; ++i)
        #pragma unroll
        for (int j = 0; j < 6; ++j) acc[i][j] = (floatx4)0.f;

    // per-lane fragment base pointers (this wave's own tiles)
    const size_t abase = (size_t)(r0 + rowg*32 + lrow)*DM + lk8*8;
    const size_t bbase = (size_t)(h*192 + colg*96 + lrow)*DM + lk8*8;
    const short* pAh = xh + abase;
    const short* pAl = xl + abase;
    const short* pBh = wh + bbase;
    const short* pBl = wl + bbase;

    short8 Ah[2][2], Al[2][2], Bh[2][6], Bl[2][6];

    // prologue: load kc=0 into buf 0
    #pragma unroll
    for (int i = 0; i < 2; ++i) {
        Ah[0][i] = *(const short8*)(pAh + (size_t)i*16*DM);
        Al[0][i] = *(const short8*)(pAl + (size_t)i*16*DM);
    }
    #pragma unroll
    for (int j = 0; j < 6; ++j) {
        Bh[0][j] = *(const short8*)(pBh + (size_t)j*16*DM);
        Bl[0][j] = *(const short8*)(pBl + (size_t)j*16*DM);
    }

    for (int kc = 0; kc < 16; ++kc) {
        const int buf = kc & 1;
        if (kc < 15) {
            const int nbuf = buf ^ 1;
            const int ko = (kc + 1)*32;
            #pragma unroll
            for (int i = 0; i < 2; ++i) {
                Ah[nbuf][i] = *(const short8*)(pAh + (size_t)i*16*DM + ko);
                Al[nbuf][i] = *(const short8*)(pAl + (size_t)i*16*DM + ko);
            }
            #pragma unroll
            for (int j = 0; j < 6; ++j) {
                Bh[nbuf][j] = *(const short8*)(pBh + (size_t)j*16*DM + ko);
                Bl[nbuf][j] = *(const short8*)(pBl + (size_t)j*16*DM + ko);
            }
        }
        #pragma unroll
        for (int j = 0; j < 6; ++j) {
            #pragma unroll
            for (int i = 0; i < 2; ++i) {
                acc[i][j] = __builtin_amdgcn_mfma_f32_16x16x32_bf16(Ah[buf][i], Bh[buf][j], acc[i][j], 0, 0, 0);
                acc[i][j] = __builtin_amdgcn_mfma_f32_16x16x32_bf16(Al[buf][i], Bh[buf][j], acc[i][j], 0, 0, 0);
                acc[i][j] = __builtin_amdgcn_mfma_f32_16x16x32_bf16(Ah[buf][i], Bl[buf][j], acc[i][j], 0, 0, 0);
            }
        }
    }

    // epilogue in two 32-row halves (Cl = 32x192 fp32 = 24KB)
    sb[tid] = 0.f;
    const float inv_scale = 1.0f / (8.0f * expf(beta[h]));
    float kacc0 = 0.f, kacc1 = 0.f, vacc0 = 0.f, vacc1 = 0.f;

    #pragma unroll
    for (int half = 0; half < 2; ++half) {
        __syncthreads();
        if (rowg == half) {
            #pragma unroll
            for (int i = 0; i < 2; ++i) {
                #pragma unroll
                for (int j = 0; j < 6; ++j) {
                    int col = colg*96 + j*16 + lrow;
                    float bias = bcat[h*192 + col];
                    #pragma unroll
                    for (int reg = 0; reg < 4; ++reg) {
                        int row = i*16 + lk8*4 + reg;   // 0..31 within half
                        Cl[row*192 + col] = acc[i][j][reg] + bias;
                    }
                }
            }
        }
        __syncthreads();
        for (int i2 = w; i2 < 32; i2 += 4) {
            float qv = Cl[i2*192 + lane];
            float kv = Cl[i2*192 + 64 + lane];
            float vv = Cl[i2*192 + 128 + lane];
            int r = r0 + half*32 + i2;
            int s = r >> 1;
            int b = r & 1;
            if ((s & 63) == 63) {
                int wi = s >> 6;
                qsel[((size_t)(b*NH + h)*T_KEEP + wi)*64 + lane] = qv;
            }
            float p = qv * kv;
            #pragma unroll
            for (int off = 32; off > 0; off >>= 1) p += __shfl_xor(p, off, 64);
            float sig = 1.0f / (1.0f + expf(-p * inv_scale));
            if (b == 0) { kacc0 += sig*kv; vacc0 += sig*vv; }
            else        { kacc1 += sig*kv; vacc1 += sig*vv; }
        }
    }
    __syncthreads();

    atomicAdd(&sb[  0 + lane], kacc0);
    atomicAdd(&sb[ 64 + lane], vacc0);
    atomicAdd(&sb[128 + lane], kacc1);
    atomicAdd(&sb[192 + lane], vacc1);
    __syncthreads();
    {
        int b   = tid >> 7;
        int sel = (tid >> 6) & 1;
        int j   = tid & 63;
        int z   = b*NH + h;
        atomicAdd(&gbar[sel*1024 + z*64 + j], sb[tid]);
    }
}

// ------------- Kernel 2: per-z coef (softmax) + G row ------------------------
// grid 16 (z = b*8+h), block 256. coef[z][wi] via thread-parallel partials;
// G[z][c] = sum_j vbar[z][j]*Wo[c][h*64+j] with 2 c per thread.
__global__ __launch_bounds__(256) void headk(
    const float* __restrict__ qsel, const float* __restrict__ beta,
    const float* __restrict__ gbar, const float* __restrict__ Wo,
    float* __restrict__ coef, float* __restrict__ G)
{
    const int z = blockIdx.x;
    const int h = z & 7;
    const int tid = threadIdx.x;

    __shared__ float s_kb[64], s_vb[64];
    __shared__ float s_part[T_KEEP][8];

    if (tid < 64) {
        s_kb[tid] = gbar[z*64 + tid];
        s_vb[tid] = gbar[1024 + z*64 + tid];
    }
    __syncthreads();

    // scores: thread (wi = tid>>3, jg = tid&7) does an 8-wide partial dot
    {
        int wi = tid >> 3, jg = tid & 7;
        const float* qrow = &qsel[((size_t)z*T_KEEP + wi)*64 + jg*8];
        float4 q1 = *(const float4*)qrow;
        float4 q2 = *(const float4*)(qrow + 4);
        int j0 = jg*8;
        float p = q1.x*s_kb[j0] + q1.y*s_kb[j0+1] + q1.z*s_kb[j0+2] + q1.w*s_kb[j0+3]
                + q2.x*s_kb[j0+4] + q2.y*s_kb[j0+5] + q2.z*s_kb[j0+6] + q2.w*s_kb[j0+7];
        s_part[wi][jg] = p;
    }
    __syncthreads();
    if (tid < T_KEEP) {
        float sc = 0.f;
        #pragma unroll
        for (int gg = 0; gg < 8; ++gg) sc += s_part[tid][gg];
        sc *= 1.0f / (8.0f * expf(beta[h]));
        float m = sc;
        #pragma unroll
        for (int off = 16; off > 0; off >>= 1) m = fmaxf(m, __shfl_xor(m, off, 64));
        m = fmaxf(m, 0.f);                       // sink logit = 0
        float e = expf(sc - m);
        float d = e;
        #pragma unroll
        for (int off = 16; off > 0; off >>= 1) d += __shfl_xor(d, off, 64);
        d += expf(-m);                           // sink term
        float c = e / d;
        if (tid == T_KEEP-1) c += 1.0f;          // iter-0 contribution
        coef[z*T_KEEP + tid] = c;
    }

    // G: per-thread 64-MAC dots (2 columns per thread)
    for (int c = tid; c < DM; c += 256) {
        const float* wrow = &Wo[(size_t)c*DM + h*64];
        float a = 0.f;
        #pragma unroll
        for (int j = 0; j < 64; j += 4) {
            float4 wv = *(const float4*)&wrow[j];
            a += wv.x*s_vb[j] + wv.y*s_vb[j+1] + wv.z*s_vb[j+2] + wv.w*s_vb[j+3];
        }
        G[(size_t)z*DM + c] = a;
    }
}

// ------------- Kernel 3: output rows from coef x G ---------------------------
// grid 64: block a -> row ROW0+a (a = wi*2+b); coalesced G reads, 8 FMA/elem.
__global__ __launch_bounds__(256) void outk3(
    const float* __restrict__ coef, const float* __restrict__ G,
    const float* __restrict__ bo, float* __restrict__ out)
{
    const int a = blockIdx.x;
    const int b = a & 1;
    const int wi = a >> 1;
    const int tid = threadIdx.x;
    __shared__ float s_cf[NH];
    if (tid < NH) s_cf[tid] = coef[(b*NH + tid)*T_KEEP + wi];
    __syncthreads();
    for (int c = tid; c < DM; c += 256) {
        float v = bo[c];
        #pragma unroll
        for (int h = 0; h < NH; ++h)
            v += s_cf[h] * G[(size_t)(b*NH + h)*DM + c];
        out[(size_t)(ROW0 + a)*DM + c] = v;
    }
}

extern "C" void kernel_launch(void* const* d_in, const int* in_sizes, int n_in,
                              void* d_out, int out_size, void* d_ws, size_t ws_size,
                              hipStream_t stream) {
    const float* x    = (const float*)d_in[0];
    const float* Wq   = (const float*)d_in[1];
    const float* bq   = (const float*)d_in[2];
    const float* Wk   = (const float*)d_in[3];
    const float* bk   = (const float*)d_in[4];
    const float* Wv   = (const float*)d_in[5];
    const float* bv   = (const float*)d_in[6];
    const float* Wo   = (const float*)d_in[7];
    const float* bo   = (const float*)d_in[8];
    const float* beta = (const float*)d_in[9];

    char* ws = (char*)d_ws;
    float* gbar = (float*)(ws + 0);           //   8 KB
    float* qsel = (float*)(ws + 8192);        // 128 KB
    float* bcat = (float*)(ws + 139264);      //   8 KB
    float* coef = (float*)(ws + 147456);      //   2 KB
    float* G    = (float*)(ws + 149504);      //  32 KB
    short* xh   = (short*)(ws + 182272);      //   4 MB
    short* xl   = (short*)(ws + 182272 + 4194304);
    short* wh   = (short*)(ws + 182272 + 2*4194304);
    short* wl   = (short*)(ws + 182272 + 2*4194304 + 1572864);
    float* out  = (float*)d_out;

    convert<<<1024, 256, 0, stream>>>(x, Wq, Wk, Wv, bq, bk, bv, bo,
                                      xh, xl, wh, wl, bcat, gbar, out);
    dim3 g1(RTOT/64, NH);
    qkv_gemm<<<g1, 256, 0, stream>>>(xh, xl, wh, wl, bcat, beta, gbar, qsel);
    headk<<<16, 256, 0, stream>>>(qsel, beta, gbar, Wo, coef, G);
    outk3<<<64, 256, 0, stream>>>(coef, G, bo, out);
}

// Round 8
// 132.629 us; speedup vs baseline: 1.3696x; 1.2067x over previous
//
#include <hip/hip_runtime.h>
#include <hip/hip_bf16.h>
#include <math.h>

#define S_LEN 2048
#define BSZ 2
#define DM 512
#define NH 8
#define HD 64
#define RTOT (S_LEN*BSZ)             // 4096 rows, row r = s*BSZ + b
#define T_KEEP 32
#define ROW0 ((S_LEN - T_KEEP)*BSZ)  // 4032
#define NXELEM (RTOT*DM)             // 2097152
#define NWROW  (NH*192)              // 1536
#define NWELEM (NWROW*DM)            // 786432

typedef __attribute__((ext_vector_type(8))) _Float16 half8;
typedef __attribute__((ext_vector_type(4))) float floatx4;

__device__ __forceinline__ short cvt1(float v) {
    _Float16 h = (_Float16)v;
    return __builtin_bit_cast(short, h);
}

// ---- Kernel 0: fp32 -> fp16 planes + bias concat + gbar zero + bg fill --------
__global__ __launch_bounds__(256) void convert(
    const float* __restrict__ x,
    const float* __restrict__ Wq, const float* __restrict__ Wk, const float* __restrict__ Wv,
    const float* __restrict__ bq, const float* __restrict__ bk, const float* __restrict__ bv,
    const float* __restrict__ bo,
    short* __restrict__ xf, short* __restrict__ wf, float* __restrict__ bcat,
    float* __restrict__ gbar, float* __restrict__ out)
{
    const int g = blockIdx.x*blockDim.x + threadIdx.x;
    const int stride = gridDim.x*blockDim.x;
    const int total4 = (NXELEM + NWELEM)/4;
    for (int i = g; i < total4; i += stride) {
        float4 v; size_t dst; short* d;
        if (i < NXELEM/4) {
            v = ((const float4*)x)[i];
            dst = (size_t)i*4; d = xf;
        } else {
            int j = i - NXELEM/4;
            int e = j*4;
            int R = e >> 9;
            int k = e & 511;
            int t = R >> 6;                 // = h*3 + m
            int hh = (t*683) >> 11;         // t/3 for t<24
            int m = t - 3*hh;
            int c = R & 63;
            const float* W = (m == 0 ? Wq : (m == 1 ? Wk : Wv));
            v = *(const float4*)&W[(size_t)(hh*HD + c)*DM + k];
            dst = (size_t)R*DM + k; d = wf;
        }
        short4 hv;
        hv.x = cvt1(v.x); hv.y = cvt1(v.y); hv.z = cvt1(v.z); hv.w = cvt1(v.w);
        *(short4*)&d[dst] = hv;
    }
    // background fill: rows < ROW0 of out are just bo
    {
        const float4* b4 = (const float4*)bo;
        float4* o4 = (float4*)out;
        const int fill4 = ROW0*DM/4;
        for (int i = g; i < fill4; i += stride) o4[i] = b4[i & 127];
    }
    if (g < NWROW) {
        int t = g >> 6;
        int hh = (t*683) >> 11;
        int m = t - 3*hh;
        int c = g & 63;
        bcat[g] = (m == 0 ? bq : (m == 1 ? bk : bv))[hh*HD + c];
    }
    if (g < 2048) gbar[g] = 0.f;
}

// ------------- Kernel 1: fp16 MFMA qkv GEMM, barrier-free K loop ---------------
// grid (64, 8): block = 64 rows x head h's 192 cols. Waves 2x2 (32r x 96c each).
// Fragments loaded directly from global (fragment layout == memory layout:
// lane l -> row l&15, k (l>>4)*8, 16B). Register double-buffer, full unroll.
__global__ __launch_bounds__(256) void qkv_gemm(
    const _Float16* __restrict__ xf, const _Float16* __restrict__ wf,
    const float* __restrict__ bcat, const float* __restrict__ beta,
    float* __restrict__ gbar, float* __restrict__ qsel)
{
    __shared__ __align__(16) float Cl[32*192];   // 24KB C-dump (two halves)
    __shared__ float sb[256];

    const int tid  = threadIdx.x;
    const int w    = tid >> 6;
    const int lane = tid & 63;
    const int lrow = lane & 15;
    const int lk8  = lane >> 4;
    const int h    = blockIdx.y;
    const int r0   = blockIdx.x * 64;
    const int rowg = w >> 1;
    const int colg = w & 1;

    floatx4 acc[2][6];
    #pragma unroll
    for (int i = 0; i < 2; ++i)
        #pragma unroll
        for (int j = 0; j < 6; ++j) acc[i][j] = (floatx4)0.f;

    const _Float16* pA = xf + (size_t)(r0 + rowg*32 + lrow)*DM + lk8*8;
    const _Float16* pB = wf + (size_t)(h*192 + colg*96 + lrow)*DM + lk8*8;

    half8 Ab[2][2], Bb[2][6];
    #pragma unroll
    for (int i = 0; i < 2; ++i) Ab[0][i] = *(const half8*)(pA + (size_t)i*16*DM);
    #pragma unroll
    for (int j = 0; j < 6; ++j) Bb[0][j] = *(const half8*)(pB + (size_t)j*16*DM);

    #pragma unroll
    for (int kc = 0; kc < 16; ++kc) {
        const int buf = kc & 1;
        if (kc < 15) {
            const int nb = buf ^ 1;
            const int ko = (kc + 1)*32;
            #pragma unroll
            for (int i = 0; i < 2; ++i)
                Ab[nb][i] = *(const half8*)(pA + (size_t)i*16*DM + ko);
            #pragma unroll
            for (int j = 0; j < 6; ++j)
                Bb[nb][j] = *(const half8*)(pB + (size_t)j*16*DM + ko);
        }
        #pragma unroll
        for (int j = 0; j < 6; ++j)
            #pragma unroll
            for (int i = 0; i < 2; ++i)
                acc[i][j] = __builtin_amdgcn_mfma_f32_16x16x32_f16(Ab[buf][i], Bb[buf][j], acc[i][j], 0, 0, 0);
    }

    // epilogue in two 32-row halves (Cl = 32x192 fp32 = 24KB)
    sb[tid] = 0.f;
    const float inv_scale = 1.0f / (8.0f * expf(beta[h]));
    float kacc0 = 0.f, kacc1 = 0.f, vacc0 = 0.f, vacc1 = 0.f;

    #pragma unroll
    for (int half = 0; half < 2; ++half) {
        __syncthreads();
        if (rowg == half) {
            #pragma unroll
            for (int i = 0; i < 2; ++i) {
                #pragma unroll
                for (int j = 0; j < 6; ++j) {
                    int col = colg*96 + j*16 + lrow;
                    float bias = bcat[h*192 + col];
                    #pragma unroll
                    for (int reg = 0; reg < 4; ++reg) {
                        int row = i*16 + lk8*4 + reg;   // 0..31 within half
                        Cl[row*192 + col] = acc[i][j][reg] + bias;
                    }
                }
            }
        }
        __syncthreads();
        for (int i2 = w; i2 < 32; i2 += 4) {
            float qv = Cl[i2*192 + lane];
            float kv = Cl[i2*192 + 64 + lane];
            float vv = Cl[i2*192 + 128 + lane];
            int r = r0 + half*32 + i2;
            int s = r >> 1;
            int b = r & 1;
            if ((s & 63) == 63) {
                int wi = s >> 6;
                qsel[((size_t)(b*NH + h)*T_KEEP + wi)*64 + lane] = qv;
            }
            float p = qv * kv;
            #pragma unroll
            for (int off = 32; off > 0; off >>= 1) p += __shfl_xor(p, off, 64);
            float sig = 1.0f / (1.0f + expf(-p * inv_scale));
            if (b == 0) { kacc0 += sig*kv; vacc0 += sig*vv; }
            else        { kacc1 += sig*kv; vacc1 += sig*vv; }
        }
    }
    __syncthreads();

    atomicAdd(&sb[  0 + lane], kacc0);
    atomicAdd(&sb[ 64 + lane], vacc0);
    atomicAdd(&sb[128 + lane], kacc1);
    atomicAdd(&sb[192 + lane], vacc1);
    __syncthreads();
    {
        int b   = tid >> 7;
        int sel = (tid >> 6) & 1;
        int j   = tid & 63;
        int z   = b*NH + h;
        atomicAdd(&gbar[sel*1024 + z*64 + j], sb[tid]);
    }
}

// ------------- Kernel 2: per-z coef (softmax) + G row ------------------------
// grid 16 (z = b*8+h), block 256. coef via thread-parallel partials;
// G[z][c] via 4-threads-per-column partial dots + LDS reduce (no long chains).
__global__ __launch_bounds__(256) void headk(
    const float* __restrict__ qsel, const float* __restrict__ beta,
    const float* __restrict__ gbar, const float* __restrict__ Wo,
    float* __restrict__ coef, float* __restrict__ G)
{
    const int z = blockIdx.x;
    const int h = z & 7;
    const int tid = threadIdx.x;

    __shared__ float s_kb[64], s_vb[64];
    __shared__ float s_part[T_KEEP][8];
    __shared__ float s_gp[64][4];

    if (tid < 64) {
        s_kb[tid] = gbar[z*64 + tid];
        s_vb[tid] = gbar[1024 + z*64 + tid];
    }
    __syncthreads();

    // scores: thread (wi = tid>>3, jg = tid&7) does an 8-wide partial dot
    {
        int wi = tid >> 3, jg = tid & 7;
        const float* qrow = &qsel[((size_t)z*T_KEEP + wi)*64 + jg*8];
        float4 q1 = *(const float4*)qrow;
        float4 q2 = *(const float4*)(qrow + 4);
        int j0 = jg*8;
        float p = q1.x*s_kb[j0] + q1.y*s_kb[j0+1] + q1.z*s_kb[j0+2] + q1.w*s_kb[j0+3]
                + q2.x*s_kb[j0+4] + q2.y*s_kb[j0+5] + q2.z*s_kb[j0+6] + q2.w*s_kb[j0+7];
        s_part[wi][jg] = p;
    }
    __syncthreads();
    if (tid < T_KEEP) {
        float sc = 0.f;
        #pragma unroll
        for (int gg = 0; gg < 8; ++gg) sc += s_part[tid][gg];
        sc *= 1.0f / (8.0f * expf(beta[h]));
        float m = sc;
        #pragma unroll
        for (int off = 16; off > 0; off >>= 1) m = fmaxf(m, __shfl_xor(m, off, 64));
        m = fmaxf(m, 0.f);                       // sink logit = 0
        float e = expf(sc - m);
        float d = e;
        #pragma unroll
        for (int off = 16; off > 0; off >>= 1) d += __shfl_xor(d, off, 64);
        d += expf(-m);                           // sink term
        float c = e / d;
        if (tid == T_KEEP-1) c += 1.0f;          // iter-0 contribution
        coef[z*T_KEEP + tid] = c;
    }

    // G: 8 passes; 4 threads per column, 16 j each; LDS reduce
    const int cq = tid >> 2;      // 0..63 column within pass
    const int jg = tid & 3;       // j-group
    #pragma unroll
    for (int it = 0; it < 8; ++it) {
        int c = it*64 + cq;
        const float* wrow = &Wo[(size_t)c*DM + h*64 + jg*16];
        float a = 0.f;
        #pragma unroll
        for (int jj = 0; jj < 16; jj += 4) {
            float4 wv = *(const float4*)&wrow[jj];
            int j0 = jg*16 + jj;
            a += wv.x*s_vb[j0] + wv.y*s_vb[j0+1] + wv.z*s_vb[j0+2] + wv.w*s_vb[j0+3];
        }
        s_gp[cq][jg] = a;
        __syncthreads();
        if (tid < 64)
            G[(size_t)z*DM + it*64 + tid] = s_gp[tid][0] + s_gp[tid][1] + s_gp[tid][2] + s_gp[tid][3];
        __syncthreads();
    }
}

// ------------- Kernel 3: output rows from coef x G ---------------------------
// grid 64: block a -> row ROW0+a (a = wi*2+b); coalesced G reads, 8 FMA/elem.
__global__ __launch_bounds__(256) void outk3(
    const float* __restrict__ coef, const float* __restrict__ G,
    const float* __restrict__ bo, float* __restrict__ out)
{
    const int a = blockIdx.x;
    const int b = a & 1;
    const int wi = a >> 1;
    const int tid = threadIdx.x;
    __shared__ float s_cf[NH];
    if (tid < NH) s_cf[tid] = coef[(b*NH + tid)*T_KEEP + wi];
    __syncthreads();
    for (int c = tid; c < DM; c += 256) {
        float v = bo[c];
        #pragma unroll
        for (int h = 0; h < NH; ++h)
            v += s_cf[h] * G[(size_t)(b*NH + h)*DM + c];
        out[(size_t)(ROW0 + a)*DM + c] = v;
    }
}

extern "C" void kernel_launch(void* const* d_in, const int* in_sizes, int n_in,
                              void* d_out, int out_size, void* d_ws, size_t ws_size,
                              hipStream_t stream) {
    const float* x    = (const float*)d_in[0];
    const float* Wq   = (const float*)d_in[1];
    const float* bq   = (const float*)d_in[2];
    const float* Wk   = (const float*)d_in[3];
    const float* bk   = (const float*)d_in[4];
    const float* Wv   = (const float*)d_in[5];
    const float* bv   = (const float*)d_in[6];
    const float* Wo   = (const float*)d_in[7];
    const float* bo   = (const float*)d_in[8];
    const float* beta = (const float*)d_in[9];

    char* ws = (char*)d_ws;
    float* gbar = (float*)(ws + 0);           //   8 KB
    float* qsel = (float*)(ws + 8192);        // 128 KB
    float* bcat = (float*)(ws + 139264);      //   8 KB
    float* coef = (float*)(ws + 147456);      //   2 KB
    float* G    = (float*)(ws + 149504);      //  32 KB
    short* xf   = (short*)(ws + 182272);      //   4 MB
    short* wf   = (short*)(ws + 182272 + 4194304);   // 1.5 MB
    float* out  = (float*)d_out;

    convert<<<1024, 256, 0, stream>>>(x, Wq, Wk, Wv, bq, bk, bv, bo,
                                      xf, wf, bcat, gbar, out);
    dim3 g1(RTOT/64, NH);
    qkv_gemm<<<g1, 256, 0, stream>>>((const _Float16*)xf, (const _Float16*)wf,
                                     bcat, beta, gbar, qsel);
    headk<<<16, 256, 0, stream>>>(qsel, beta, gbar, Wo, coef, G);
    outk3<<<64, 256, 0, stream>>>(coef, G, bo, out);
}